// Round 10
// baseline (399.458 us; speedup 1.0000x reference)
//
#include <hip/hip_runtime.h>

#define TSEQ 256
#define FIN  32
#define HID  64

#define LOG2E    1.4426950408889634f
#define TWOLOG2E 2.8853900817779268f

typedef _Float16 f16x8 __attribute__((ext_vector_type(8)));
typedef __fp16   h16x2 __attribute__((ext_vector_type(2)));   // cvt_pkrtz return type
typedef float    f32x4 __attribute__((ext_vector_type(4)));

// Raw v_exp_f32 (flush-to-zero below 2^-126) -- OCML exp2 fixup was R8's regression.
#if __has_builtin(__builtin_amdgcn_exp2f)
__device__ __forceinline__ float fast_exp2(float x) { return __builtin_amdgcn_exp2f(x); }
#else
extern "C" __device__ float __ocml_native_exp2_f32(float);
__device__ __forceinline__ float fast_exp2(float x) { return __ocml_native_exp2_f32(x); }
#endif

// Barrier with LDS-only drain (x global prefetch spans barriers freely).
#define BAR_LDS() do { asm volatile("s_waitcnt lgkmcnt(0)" ::: "memory"); \
                       __builtin_amdgcn_s_barrier(); } while (0)

__device__ __forceinline__ float wsum(float v) {
    #pragma unroll
    for (int off = 32; off > 0; off >>= 1) v += __shfl_xor(v, off, 64);
    return v;
}

// Gates PRE-SCALED (log2e folded into weights/biases):
//   g0=-log2e*i, g1=-log2e*f, g2=2log2e*g, g3=-log2e*o
// Merged-denominator: one rcp serves sigma(f) AND sigma(i)*tanh(g).
// 5 exp + 2 rcp per cell. c clamped +-15 via med3.
__device__ __forceinline__ float lstm_cell(const f32x4 g, float& c) {
    float ei = fast_exp2(g[0]);
    float ef = fast_exp2(g[1]);
    float yg = fast_exp2(g[2]);
    float eo = fast_exp2(g[3]);
    float t1 = 1.0f + ei;
    float t2 = 1.0f + ef;
    float p  = t1 * (yg + 1.0f);
    float r  = __builtin_amdgcn_rcpf(p * t2);
    float ig = (yg - 1.0f) * t2 * r;   // sigma(i)*tanh(g)
    float sf = p * r;                  // sigma(f)
    c = fmaf(sf, c, ig);
    float cc = __builtin_amdgcn_fmed3f(c, -15.0f, 15.0f);
    float yc = fast_exp2(TWOLOG2E * cc);
    return (yc - 1.0f) * __builtin_amdgcn_rcpf((1.0f + eo) * (yc + 1.0f));
}

// R13 = R12 wave layout (8 waves x 4 tiles: waves 0-3 layer-0 "A", 4-7
// layer-1 "B") + ANTI-PHASE split-interval schedule. R10-R12 showed the
// interval is pinned at ~2080cyc by phase-aligned lockstep: all waves do
// [MFMA/LDS stall] then [cell VALU burst] simultaneously. Fix: two halves
// per interval with opposite roles, so each SIMD (1 A + 1 B wave via wid%4)
// always has exactly one cell-burst wave:
//   half1: A computes gates(i) via MFMA (regs) || B decodes DEFERRED cells
//          (gates from prev interval's half2) and writes h1
//   half2: A decodes cells -> writes h0(i)     || B computes gates via MFMA
//          (held in regs across the barrier)
// Deps: B's h1 write(half1) -> bar2 -> B's h1 read(half2): h1(i-2) written
// and read in interval i, parity P=i&1 -> buffer H1[P]. A's h0(i) write
// (half2) -> bar1 -> reads next interval. Exact same arithmetic as R12.
__global__ __launch_bounds__(512, 2)
void lstm_fused(const float* __restrict__ x,
                const float* __restrict__ w_ih0, const float* __restrict__ w_hh0,
                const float* __restrict__ b_ih0, const float* __restrict__ b_hh0,
                const float* __restrict__ w_ih1, const float* __restrict__ w_hh1,
                const float* __restrict__ b_ih1, const float* __restrict__ b_hh1,
                const float* __restrict__ ln_g, const float* __restrict__ ln_b,
                const float* __restrict__ w1, const float* __restrict__ b1,
                const float* __restrict__ w2, const float* __restrict__ b2,
                float* __restrict__ out)
{
    __shared__ __align__(16) _Float16 H0[2][16][72];  // h0 parity buffers
    __shared__ __align__(16) _Float16 H1[2][16][72];  // h1 parity buffers
    __shared__ __align__(16) float HF[16][68];        // final h1 (fp32) for head
    __shared__ __align__(16) float LNB[16][64];       // per-row layernorm buffer

    const int tid  = threadIdx.x;
    const int wave = tid >> 6;        // 0..7
    const int lane = tid & 63;
    const int q    = lane >> 4;
    const int lm   = lane & 15;
    const int q8   = q * 8;
    const int b0   = blockIdx.x * 16;

    const bool isA = wave < 4;        // waves 0-3 A, 4-7 B -> wid%4 pairs A+B per SIMD
    const int  wt  = wave & 3;
    const int rbase = (lm & 3) * 64 + (lm >> 2);
    const int dq0   = wt * 16 + q;            // d for tile 0; +4 per tile
    const float wsc = ((lm & 3) == 2) ? TWOLOG2E : -LOG2E;

    // wf: A uses [t*3+k], k={x,h0a,h0b}; B uses [t*4+k], k={ia,ib,ha,hb}
    f16x8 wf[16];
    f32x4 biasv[4];
    if (isA) {
        #pragma unroll
        for (int t = 0; t < 4; ++t) {
            const int row = rbase + wt * 16 + t * 4;
            const float* p0 = w_ih0 + row * FIN + q8;
            const float* p1 = w_hh0 + row * HID + q8;
            const float* p2 = p1 + 32;
            #pragma unroll
            for (int j = 0; j < 8; ++j) {
                wf[t * 3 + 0][j] = (_Float16)(wsc * p0[j]);
                wf[t * 3 + 1][j] = (_Float16)(wsc * p1[j]);
                wf[t * 3 + 2][j] = (_Float16)(wsc * p2[j]);
            }
            const int d = dq0 + t * 4;
            #pragma unroll
            for (int r = 0; r < 4; ++r) {
                const float s = (r == 2) ? TWOLOG2E : -LOG2E;
                biasv[t][r] = s * (b_ih0[r * 64 + d] + b_hh0[r * 64 + d]);
            }
        }
    } else {
        #pragma unroll
        for (int t = 0; t < 4; ++t) {
            const int row = rbase + wt * 16 + t * 4;
            const float* p0 = w_ih1 + row * HID + q8;
            const float* p1 = p0 + 32;
            const float* p2 = w_hh1 + row * HID + q8;
            const float* p3 = p2 + 32;
            #pragma unroll
            for (int j = 0; j < 8; ++j) {
                wf[t * 4 + 0][j] = (_Float16)(wsc * p0[j]);
                wf[t * 4 + 1][j] = (_Float16)(wsc * p1[j]);
                wf[t * 4 + 2][j] = (_Float16)(wsc * p2[j]);
                wf[t * 4 + 3][j] = (_Float16)(wsc * p3[j]);
            }
            const int d = dq0 + t * 4;
            #pragma unroll
            for (int r = 0; r < 4; ++r) {
                const float s = (r == 2) ? TWOLOG2E : -LOG2E;
                biasv[t][r] = s * (b_ih1[r * 64 + d] + b_hh1[r * 64 + d]);
            }
        }
    }

    // x prefetch registers: hold x(i) in f32 at interval-i entry (A only)
    const float* xp = x + (size_t)(b0 + lm) * TSEQ * FIN + q8;
    f32x4 xfa, xfb;
    if (isA) {
        xfa = *reinterpret_cast<const f32x4*>(xp);
        xfb = *reinterpret_cast<const f32x4*>(xp + 4);
    }

    // zero h state (both parities)
    for (int i = tid; i < 2 * 16 * 72; i += 512) {
        ((_Float16*)H0)[i] = (_Float16)0.0f;
        ((_Float16*)H1)[i] = (_Float16)0.0f;
    }
    float cs0 = 0.0f, cs1 = 0.0f, cs2 = 0.0f, cs3 = 0.0f;       // cell states
    f32x4 hb0 = {0,0,0,0}, hb1 = {0,0,0,0}, hb2 = {0,0,0,0}, hb3 = {0,0,0,0}; // B held gates
    float lastB0 = 0.0f, lastB1 = 0.0f, lastB2 = 0.0f, lastB3 = 0.0f;
    __syncthreads();

#define MFMA __builtin_amdgcn_mfma_f32_16x16x32_f16
// Interval i (P=i&1), DO_A: layer0 step i active; DO_BC: B cell phase
// (decodes held gates -> h1, write H1[P]); DO_BM: B MFMA phase (gates for
// its next cell, reads H0[P^1]=h0(i-1), H1[P]=h1(i-2), held in hb*).
#define INTERVAL(P, DO_A, DO_BC, DO_BM, XI)                                         \
    {                                                                               \
        f32x4 g0 = biasv[0], g1 = biasv[1], g2 = biasv[2], g3 = biasv[3];           \
        /* ---------------- half 1: A-MFMA || B-cells ---------------- */           \
        if (isA) {                                                                  \
            if (DO_A) {                                                             \
                f16x8 xcur;                                                         \
                {                                                                   \
                    h16x2 c0_ = __builtin_amdgcn_cvt_pkrtz(xfa[0], xfa[1]);         \
                    h16x2 c1_ = __builtin_amdgcn_cvt_pkrtz(xfa[2], xfa[3]);         \
                    h16x2 c2_ = __builtin_amdgcn_cvt_pkrtz(xfb[0], xfb[1]);         \
                    h16x2 c3_ = __builtin_amdgcn_cvt_pkrtz(xfb[2], xfb[3]);         \
                    xcur[0] = (_Float16)c0_[0]; xcur[1] = (_Float16)c0_[1];         \
                    xcur[2] = (_Float16)c1_[0]; xcur[3] = (_Float16)c1_[1];         \
                    xcur[4] = (_Float16)c2_[0]; xcur[5] = (_Float16)c2_[1];         \
                    xcur[6] = (_Float16)c3_[0]; xcur[7] = (_Float16)c3_[1];         \
                }                                                                   \
                xfa = *reinterpret_cast<const f32x4*>(xp + (size_t)(XI) * FIN);     \
                xfb = *reinterpret_cast<const f32x4*>(xp + (size_t)(XI) * FIN + 4); \
                g0 = MFMA(wf[0], xcur, g0, 0, 0, 0);                                \
                g1 = MFMA(wf[3], xcur, g1, 0, 0, 0);                                \
                g2 = MFMA(wf[6], xcur, g2, 0, 0, 0);                                \
                g3 = MFMA(wf[9], xcur, g3, 0, 0, 0);                                \
                f16x8 rh0a = *reinterpret_cast<const f16x8*>(&H0[(P) ^ 1][lm][q8]);      \
                f16x8 rh0b = *reinterpret_cast<const f16x8*>(&H0[(P) ^ 1][lm][32 + q8]); \
                g0 = MFMA(wf[1],  rh0a, g0, 0, 0, 0);                               \
                g1 = MFMA(wf[4],  rh0a, g1, 0, 0, 0);                               \
                g2 = MFMA(wf[7],  rh0a, g2, 0, 0, 0);                               \
                g3 = MFMA(wf[10], rh0a, g3, 0, 0, 0);                               \
                g0 = MFMA(wf[2],  rh0b, g0, 0, 0, 0);                               \
                g1 = MFMA(wf[5],  rh0b, g1, 0, 0, 0);                               \
                g2 = MFMA(wf[8],  rh0b, g2, 0, 0, 0);                               \
                g3 = MFMA(wf[11], rh0b, g3, 0, 0, 0);                               \
            }                                                                       \
        } else if (DO_BC) {                                                         \
            float hv0 = lstm_cell(hb0, cs0);                                        \
            float hv1 = lstm_cell(hb1, cs1);                                        \
            float hv2 = lstm_cell(hb2, cs2);                                        \
            float hv3 = lstm_cell(hb3, cs3);                                        \
            H1[P][lm][dq0]      = (_Float16)hv0;                                    \
            H1[P][lm][dq0 + 4]  = (_Float16)hv1;                                    \
            H1[P][lm][dq0 + 8]  = (_Float16)hv2;                                    \
            H1[P][lm][dq0 + 12] = (_Float16)hv3;                                    \
            lastB0 = hv0; lastB1 = hv1; lastB2 = hv2; lastB3 = hv3;                 \
        }                                                                           \
        BAR_LDS();                                                                  \
        /* ---------------- half 2: A-cells || B-MFMA ---------------- */           \
        if (isA) {                                                                  \
            if (DO_A) {                                                             \
                float hv0 = lstm_cell(g0, cs0);                                     \
                float hv1 = lstm_cell(g1, cs1);                                     \
                float hv2 = lstm_cell(g2, cs2);                                     \
                float hv3 = lstm_cell(g3, cs3);                                     \
                H0[P][lm][dq0]      = (_Float16)hv0;                                \
                H0[P][lm][dq0 + 4]  = (_Float16)hv1;                                \
                H0[P][lm][dq0 + 8]  = (_Float16)hv2;                                \
                H0[P][lm][dq0 + 12] = (_Float16)hv3;                                \
            }                                                                       \
        } else if (DO_BM) {                                                         \
            f16x8 rh0a = *reinterpret_cast<const f16x8*>(&H0[(P) ^ 1][lm][q8]);      \
            f16x8 rh0b = *reinterpret_cast<const f16x8*>(&H0[(P) ^ 1][lm][32 + q8]); \
            f16x8 rh1a = *reinterpret_cast<const f16x8*>(&H1[P][lm][q8]);            \
            f16x8 rh1b = *reinterpret_cast<const f16x8*>(&H1[P][lm][32 + q8]);       \
            hb0 = biasv[0]; hb1 = biasv[1]; hb2 = biasv[2]; hb3 = biasv[3];         \
            hb0 = MFMA(wf[0],  rh0a, hb0, 0, 0, 0);                                 \
            hb1 = MFMA(wf[4],  rh0a, hb1, 0, 0, 0);                                 \
            hb2 = MFMA(wf[8],  rh0a, hb2, 0, 0, 0);                                 \
            hb3 = MFMA(wf[12], rh0a, hb3, 0, 0, 0);                                 \
            hb0 = MFMA(wf[1],  rh0b, hb0, 0, 0, 0);                                 \
            hb1 = MFMA(wf[5],  rh0b, hb1, 0, 0, 0);                                 \
            hb2 = MFMA(wf[9],  rh0b, hb2, 0, 0, 0);                                 \
            hb3 = MFMA(wf[13], rh0b, hb3, 0, 0, 0);                                 \
            hb0 = MFMA(wf[2],  rh1a, hb0, 0, 0, 0);                                 \
            hb1 = MFMA(wf[6],  rh1a, hb1, 0, 0, 0);                                 \
            hb2 = MFMA(wf[10], rh1a, hb2, 0, 0, 0);                                 \
            hb3 = MFMA(wf[14], rh1a, hb3, 0, 0, 0);                                 \
            hb0 = MFMA(wf[3],  rh1b, hb0, 0, 0, 0);                                 \
            hb1 = MFMA(wf[7],  rh1b, hb1, 0, 0, 0);                                 \
            hb2 = MFMA(wf[11], rh1b, hb2, 0, 0, 0);                                 \
            hb3 = MFMA(wf[15], rh1b, hb3, 0, 0, 0);                                 \
        }                                                                           \
        BAR_LDS();                                                                  \
    }

    // i=0 (P=0): A only. i=1 (P=1): A + B-MFMA(gates1(0): h0(0), h1(-1)=0).
    INTERVAL(0, true, false, false, 1)
    INTERVAL(1, true, false, true, 2)

    // main: intervals 2..255 as 127 (even,odd) pairs, all phases active.
    #pragma unroll 1
    for (int ii = 0; ii < 127; ++ii) {
        const int i0 = 2 * ii + 2;
        const int xiB = (i0 + 2 > 255) ? 255 : i0 + 2;
        INTERVAL(0, true, true, true, i0 + 1)
        INTERVAL(1, true, true, true, xiB)
    }

    // i=256 (P=0): B cells h1(254); B-MFMA gates1(255) (h0(255), h1(254)).
    INTERVAL(0, false, true, true, 0)
    // i=257 (P=1): B cells gates1(255) -> h1(255) = lastB.
    INTERVAL(1, false, true, false, 0)

#undef INTERVAL
#undef MFMA

    if (!isA) {
        HF[lm][dq0]      = lastB0;
        HF[lm][dq0 + 4]  = lastB1;
        HF[lm][dq0 + 8]  = lastB2;
        HF[lm][dq0 + 12] = lastB3;
    }
    __syncthreads();

    // ============ Head: LayerNorm + MLP (wave w -> rows w, w+8) ============
    const float lngv = ln_g[lane], lnbv = ln_b[lane];
    const float b1v = b1[lane], w2v = w2[lane];
    const float* w1row = w1 + lane * 64;
    #pragma unroll
    for (int rr = wave; rr < 16; rr += 8) {
        float v  = HF[rr][lane];
        float mu = wsum(v) * (1.0f / 64.0f);
        float dv = v - mu;
        float var = wsum(dv * dv) * (1.0f / 64.0f);
        float ln = dv * rsqrtf(var + 1e-5f) * lngv + lnbv;
        LNB[rr][lane] = ln;
        float s = b1v;
        #pragma unroll
        for (int dd = 0; dd < 64; ++dd)
            s = fmaf(LNB[rr][dd], w1row[dd], s);
        s = fmaxf(s, 0.0f);
        float y = wsum(s * w2v);
        if (lane == 0) out[b0 + rr] = y + b2[0];
    }
}

extern "C" void kernel_launch(void* const* d_in, const int* in_sizes, int n_in,
                              void* d_out, int out_size, void* d_ws, size_t ws_size,
                              hipStream_t stream) {
    const float* x     = (const float*)d_in[0];
    const float* w_ih0 = (const float*)d_in[1];
    const float* w_hh0 = (const float*)d_in[2];
    const float* b_ih0 = (const float*)d_in[3];
    const float* b_hh0 = (const float*)d_in[4];
    const float* w_ih1 = (const float*)d_in[5];
    const float* w_hh1 = (const float*)d_in[6];
    const float* b_ih1 = (const float*)d_in[7];
    const float* b_hh1 = (const float*)d_in[8];
    const float* ln_g  = (const float*)d_in[9];
    const float* ln_b  = (const float*)d_in[10];
    const float* w1    = (const float*)d_in[11];
    const float* b1    = (const float*)d_in[12];
    const float* w2    = (const float*)d_in[13];
    const float* b2    = (const float*)d_in[14];
    lstm_fused<<<dim3(256), dim3(512), 0, stream>>>(
        x, w_ih0, w_hh0, b_ih0, b_hh0,
        w_ih1, w_hh1, b_ih1, b_hh1,
        ln_g, ln_b, w1, b1, w2, b2, (float*)d_out);
}